// Round 5
// baseline (271.843 us; speedup 1.0000x reference)
//
#include <hip/hip_runtime.h>
#include <cstddef>

#define NB   16
#define CIN  512
#define NTOK 1600   // 40*40
#define HCH  64
#define LDA  72     // padded LDS row stride (bf16 elems), mult of 8 for 16B loads

typedef __attribute__((ext_vector_type(8))) short bf16x8;
typedef __attribute__((ext_vector_type(4))) float f32x4;

__device__ __forceinline__ unsigned short f2bf(float x) {
    union { float f; unsigned u; } v; v.f = x;
    unsigned r = v.u + 0x7FFFu + ((v.u >> 16) & 1u);   // round-nearest-even
    return (unsigned short)(r >> 16);
}

// ---------------------------------------------------------------------------
// Weight prep: Wt[3][64h][512c] = {wq,wk,wv}^T ; WoT[512c][64j] = wo^T
// ---------------------------------------------------------------------------
__global__ void __launch_bounds__(256) wprep_kernel(
    const float* __restrict__ wq, const float* __restrict__ wk,
    const float* __restrict__ wv, const float* __restrict__ wo,
    unsigned short* __restrict__ Wt, unsigned short* __restrict__ WoT)
{
    const int gid = blockIdx.x * 256 + threadIdx.x;
    if (gid < 3 * HCH * (CIN / 8)) {               // 12288 Wt threads
        const int h  = gid & 63;
        const int c8 = (gid >> 6) & 63;
        const int t  = gid >> 12;
        const float* w = (t == 0) ? wq : (t == 1) ? wk : wv;
        ushort4 lo, hi;
        lo.x = f2bf(w[(size_t)(c8 * 8 + 0) * HCH + h]);
        lo.y = f2bf(w[(size_t)(c8 * 8 + 1) * HCH + h]);
        lo.z = f2bf(w[(size_t)(c8 * 8 + 2) * HCH + h]);
        lo.w = f2bf(w[(size_t)(c8 * 8 + 3) * HCH + h]);
        hi.x = f2bf(w[(size_t)(c8 * 8 + 4) * HCH + h]);
        hi.y = f2bf(w[(size_t)(c8 * 8 + 5) * HCH + h]);
        hi.z = f2bf(w[(size_t)(c8 * 8 + 6) * HCH + h]);
        hi.w = f2bf(w[(size_t)(c8 * 8 + 7) * HCH + h]);
        ushort4* dst = (ushort4*)(Wt + ((size_t)t * HCH + h) * CIN + c8 * 8);
        dst[0] = lo; dst[1] = hi;
    } else {                                        // 4096 WoT threads
        const int g  = gid - 3 * HCH * (CIN / 8);
        const int c  = g & 511;
        const int j8 = g >> 9;
        ushort4 lo, hi;
        lo.x = f2bf(wo[(size_t)(j8 * 8 + 0) * CIN + c]);
        lo.y = f2bf(wo[(size_t)(j8 * 8 + 1) * CIN + c]);
        lo.z = f2bf(wo[(size_t)(j8 * 8 + 2) * CIN + c]);
        lo.w = f2bf(wo[(size_t)(j8 * 8 + 3) * CIN + c]);
        hi.x = f2bf(wo[(size_t)(j8 * 8 + 4) * CIN + c]);
        hi.y = f2bf(wo[(size_t)(j8 * 8 + 5) * CIN + c]);
        hi.z = f2bf(wo[(size_t)(j8 * 8 + 6) * CIN + c]);
        hi.w = f2bf(wo[(size_t)(j8 * 8 + 7) * CIN + c]);
        ushort4* dst = (ushort4*)(WoT + (size_t)c * HCH + j8 * 8);
        dst[0] = lo; dst[1] = hi;
    }
}

// ---------------------------------------------------------------------------
// Projections (MFMA), zero-LDS / zero-barrier.
// A-fragments gathered directly from rgb/hsi (8 stride-NTOK f32 loads, 64B
// coalesced per quad-group); B-fragments = contiguous b128 from Wt (L2-hot).
// blockIdx.y==0: Q,K from rgb (Q pre-scaled by 0.125/ln2); ==1: V from hsi.
// Q,K stored [b][n][h]; V stored Vt[b][h][n].
// ---------------------------------------------------------------------------
__global__ void __launch_bounds__(256) proj_kernel(
    const float* __restrict__ rgb, const float* __restrict__ hsi,
    const unsigned short* __restrict__ Wt,
    unsigned short* __restrict__ Q, unsigned short* __restrict__ K,
    unsigned short* __restrict__ Vt)
{
    const int which = blockIdx.y;                 // 0: QK, 1: V
    const int b    = blockIdx.x / 25;
    const int n0   = (blockIdx.x % 25) * 64;
    const int tid  = threadIdx.x;
    const int wv_  = tid >> 6;
    const int lane = tid & 63;
    const int l16  = lane & 15, quad = lane >> 4;

    const float* __restrict__ src = which ? hsi : rgb;
    const unsigned short* __restrict__ wbase = Wt + (which ? (size_t)2 * HCH * CIN : 0);
    const int nT = which ? 1 : 2;

    const int n = n0 + wv_ * 16 + l16;            // this lane's token (m dim)
    const float* __restrict__ xcol = src + (size_t)b * CIN * NTOK + n;

    f32x4 acc[2][4];
    #pragma unroll
    for (int t = 0; t < 2; ++t)
        #pragma unroll
        for (int nt = 0; nt < 4; ++nt)
            #pragma unroll
            for (int r = 0; r < 4; ++r) acc[t][nt][r] = 0.f;

    #pragma unroll 2
    for (int c0 = 0; c0 < CIN; c0 += 64) {
        // A fragments: k = c0 + k0*32 + quad*8 + j
        bf16x8 af[2];
        #pragma unroll
        for (int k0 = 0; k0 < 2; ++k0) {
            const float* p = xcol + (size_t)(c0 + k0 * 32 + quad * 8) * NTOK;
            bf16x8 v;
            #pragma unroll
            for (int j = 0; j < 8; ++j)
                v[j] = (short)f2bf(p[(size_t)j * NTOK]);
            af[k0] = v;
        }
        for (int t = 0; t < nT; ++t)
            #pragma unroll
            for (int k0 = 0; k0 < 2; ++k0)
                #pragma unroll
                for (int nt = 0; nt < 4; ++nt) {
                    const bf16x8 bw = *((const bf16x8*)(wbase +
                        ((size_t)t * HCH + nt * 16 + l16) * CIN + c0 + k0 * 32 + quad * 8));
                    acc[t][nt] = __builtin_amdgcn_mfma_f32_16x16x32_bf16(af[k0], bw, acc[t][nt], 0, 0, 0);
                }
    }

    if (which == 0) {
        const float qscale = 0.18033688f;          // 0.125 / ln(2)
        #pragma unroll
        for (int nt = 0; nt < 4; ++nt) {
            const int h = nt * 16 + l16;
            #pragma unroll
            for (int r = 0; r < 4; ++r) {
                const int nn = n0 + wv_ * 16 + quad * 4 + r;
                Q[((size_t)b * NTOK + nn) * HCH + h] = f2bf(acc[0][nt][r] * qscale);
                K[((size_t)b * NTOK + nn) * HCH + h] = f2bf(acc[1][nt][r]);
            }
        }
    } else {
        #pragma unroll
        for (int nt = 0; nt < 4; ++nt) {
            const int h = nt * 16 + l16;
            ushort4 pv;
            pv.x = f2bf(acc[0][nt][0]); pv.y = f2bf(acc[0][nt][1]);
            pv.z = f2bf(acc[0][nt][2]); pv.w = f2bf(acc[0][nt][3]);
            *((ushort4*)(Vt + ((size_t)b * HCH + h) * NTOK + n0 + wv_ * 16 + quad * 4)) = pv;
        }
    }
}

// ---------------------------------------------------------------------------
// Attention, no-max softmax (exp2, scale folded into Q), split-K across the
// 4 waves. Block = (b, 16-query tile of 100); wave w does kt = w, w+4, ...
// Barrier-free K-loop (double-buffered per-wave P strips); two-barrier merge.
// blockIdx.x = qt*16 + b keeps each batch's K/V on one XCD's L2.
// ---------------------------------------------------------------------------
__global__ void __launch_bounds__(256) attn_kernel(
    const unsigned short* __restrict__ Q, const unsigned short* __restrict__ K,
    const unsigned short* __restrict__ Vt, unsigned short* __restrict__ Rt2)
{
    // P strips: 4 waves x 2 bufs x 16 rows x LDA x 2B = 18432 B,
    // aliased with merge buffers Osh[4][16][68] f32 (17408 B) + lsh[4][16].
    __shared__ __align__(16) unsigned char smem[4 * 2 * 16 * LDA * 2];

    const int b    = blockIdx.x & 15;
    const int qt   = blockIdx.x >> 4;          // 0..99
    const int tid  = threadIdx.x;
    const int wv_  = tid >> 6;
    const int lane = tid & 63;
    const int l16  = lane & 15, quad = lane >> 4;

    const unsigned short* Qg = Q  + ((size_t)b * NTOK + qt * 16) * HCH;
    const unsigned short* Kg = K  + (size_t)b * NTOK * HCH;
    const unsigned short* Vg = Vt + (size_t)b * HCH * NTOK;

    unsigned short* PsW = (unsigned short*)smem + wv_ * (2 * 16 * LDA);

    bf16x8 qa[2];
    #pragma unroll
    for (int k0 = 0; k0 < 2; ++k0)
        qa[k0] = *((const bf16x8*)(Qg + (size_t)l16 * HCH + k0 * 32 + quad * 8));

    f32x4 o[4];
    float rs[4];
    #pragma unroll
    for (int r = 0; r < 4; ++r) rs[r] = 0.f;
    #pragma unroll
    for (int nt = 0; nt < 4; ++nt)
        #pragma unroll
        for (int r = 0; r < 4; ++r) o[nt][r] = 0.f;

    int buf = 0;
    for (int kt = wv_; kt < 25; kt += 4, buf ^= 1) {
        unsigned short* Pb = PsW + buf * (16 * LDA);

        // ---- K fragments, S = Q K^T ----
        bf16x8 kb[2][4];
        #pragma unroll
        for (int k0 = 0; k0 < 2; ++k0)
            #pragma unroll
            for (int nt = 0; nt < 4; ++nt)
                kb[k0][nt] = *((const bf16x8*)(Kg + ((size_t)(kt * 64 + nt * 16 + l16)) * HCH + k0 * 32 + quad * 8));

        f32x4 s[4];
        #pragma unroll
        for (int nt = 0; nt < 4; ++nt)
            #pragma unroll
            for (int r = 0; r < 4; ++r) s[nt][r] = 0.f;
        #pragma unroll
        for (int k0 = 0; k0 < 2; ++k0)
            #pragma unroll
            for (int nt = 0; nt < 4; ++nt)
                s[nt] = __builtin_amdgcn_mfma_f32_16x16x32_bf16(qa[k0], kb[k0][nt], s[nt], 0, 0, 0);

        // ---- V fragments (issue early; consumed after softmax) ----
        bf16x8 vb[2][4];
        #pragma unroll
        for (int k0 = 0; k0 < 2; ++k0)
            #pragma unroll
            for (int nt = 0; nt < 4; ++nt)
                vb[k0][nt] = *((const bf16x8*)(Vg + ((size_t)(nt * 16 + l16)) * NTOK + kt * 64 + k0 * 32 + quad * 8));

        // ---- P = exp2(S); row sums; pack into per-wave LDS strip ----
        #pragma unroll
        for (int r = 0; r < 4; ++r)
            #pragma unroll
            for (int nt = 0; nt < 4; ++nt) {
                const float e = __builtin_amdgcn_exp2f(s[nt][r]);
                rs[r] += e;
                Pb[(quad * 4 + r) * LDA + nt * 16 + l16] = f2bf(e);
            }

        // ---- O += P V  (same-wave LDS, no barrier) ----
        #pragma unroll
        for (int k0 = 0; k0 < 2; ++k0) {
            const bf16x8 pa = *((const bf16x8*)(Pb + l16 * LDA + k0 * 32 + quad * 8));
            #pragma unroll
            for (int nt = 0; nt < 4; ++nt)
                o[nt] = __builtin_amdgcn_mfma_f32_16x16x32_bf16(pa, vb[k0][nt], o[nt], 0, 0, 0);
        }
    }

    // ---- reduce row sums across the 16 lanes of each row ----
    #pragma unroll
    for (int r = 0; r < 4; ++r)
        #pragma unroll
        for (int msk = 1; msk < 16; msk <<= 1)
            rs[r] += __shfl_xor(rs[r], msk, 16);

    // ---- merge partial O / l across the 4 waves (aliased LDS) ----
    __syncthreads();
    float* Osh = (float*)smem;                       // [(w*16+q)][68]
    float* lsh = (float*)(smem + 4 * 16 * 68 * 4);   // [w*16+q]
    #pragma unroll
    for (int nt = 0; nt < 4; ++nt)
        #pragma unroll
        for (int r = 0; r < 4; ++r)
            Osh[(size_t)(wv_ * 16 + quad * 4 + r) * 68 + nt * 16 + l16] = o[nt][r];
    if (l16 == 0)
        #pragma unroll
        for (int r = 0; r < 4; ++r)
            lsh[wv_ * 16 + quad * 4 + r] = rs[r];
    __syncthreads();

    // lane outputs h = wv_*16+l16 for its 4 q rows; Rt2[b][t][h][j]
    const int t  = qt >> 2;
    const int jb = (qt & 3) * 16;
    const int h  = wv_ * 16 + l16;
    unsigned short* Rg = Rt2 + ((size_t)(b * 25 + t) * HCH + h) * HCH + jb;
    ushort4 pk;
    unsigned short pkv[4];
    #pragma unroll
    for (int r = 0; r < 4; ++r) {
        const int q = quad * 4 + r;
        float val = 0.f, L = 0.f;
        #pragma unroll
        for (int w = 0; w < 4; ++w) {
            val += Osh[(size_t)(w * 16 + q) * 68 + h];
            L   += lsh[w * 16 + q];
        }
        pkv[r] = f2bf(val / L);
    }
    pk.x = pkv[0]; pk.y = pkv[1]; pk.z = pkv[2]; pk.w = pkv[3];
    *((ushort4*)(Rg + quad * 4)) = pk;
}

// ---------------------------------------------------------------------------
// Output projection: out[b][c][h*25+t] = sum_j wo[j][c] * Rt2[b][t][h][j]
// Grid (16 b, 8 c-tiles, 25 n-tiles): one 64x64 output tile per block.
// ---------------------------------------------------------------------------
__global__ void __launch_bounds__(256) outproj_kernel(
    const unsigned short* __restrict__ Rt2, const unsigned short* __restrict__ WoT,
    float* __restrict__ out)
{
    __shared__ __align__(16) unsigned short Aw[64 * LDA];

    const int b    = blockIdx.x;
    const int ct   = blockIdx.y;
    const int nt64 = blockIdx.z;
    const int tid  = threadIdx.x;
    const int wv_  = tid >> 6;
    const int lane = tid & 63;
    const int l16  = lane & 15, quad = lane >> 4;

    #pragma unroll
    for (int r = 0; r < 2; ++r) {
        const int task = tid + r * 256;
        const int row = task >> 3, ch = task & 7;
        *((int4*)(Aw + row * LDA + ch * 8)) =
            *((const int4*)(WoT + ((size_t)(ct * 64 + row)) * HCH + ch * 8));
    }
    __syncthreads();

    const int n = nt64 * 64 + wv_ * 16 + l16;
    const int h = n / 25, t = n % 25;
    const unsigned short* bsrc = Rt2 + ((size_t)(b * 25 + t) * HCH + h) * HCH;

    f32x4 acc[4];
    #pragma unroll
    for (int mt = 0; mt < 4; ++mt)
        #pragma unroll
        for (int r = 0; r < 4; ++r) acc[mt][r] = 0.f;

    #pragma unroll
    for (int k0 = 0; k0 < 2; ++k0) {
        const bf16x8 bv = *((const bf16x8*)(bsrc + k0 * 32 + quad * 8));
        #pragma unroll
        for (int mt = 0; mt < 4; ++mt) {
            const bf16x8 av = *((const bf16x8*)(Aw + (mt * 16 + l16) * LDA + k0 * 32 + quad * 8));
            acc[mt] = __builtin_amdgcn_mfma_f32_16x16x32_bf16(av, bv, acc[mt], 0, 0, 0);
        }
    }
    #pragma unroll
    for (int mt = 0; mt < 4; ++mt)
        #pragma unroll
        for (int r = 0; r < 4; ++r)
            out[((size_t)b * CIN + ct * 64 + mt * 16 + quad * 4 + r) * NTOK + n] = acc[mt][r];
}

// ---------------------------------------------------------------------------
extern "C" void kernel_launch(void* const* d_in, const int* in_sizes, int n_in,
                              void* d_out, int out_size, void* d_ws, size_t ws_size,
                              hipStream_t stream)
{
    const float* rgb = (const float*)d_in[0];
    const float* hsi = (const float*)d_in[1];
    const float* wq  = (const float*)d_in[2];
    const float* wk  = (const float*)d_in[3];
    const float* wv  = (const float*)d_in[4];
    const float* wo  = (const float*)d_in[5];
    float* out = (float*)d_out;

    unsigned short* Wt  = (unsigned short*)d_ws;
    unsigned short* WoT = Wt  + (size_t)3 * HCH * CIN;
    unsigned short* Qb  = WoT + (size_t)CIN * HCH;
    unsigned short* Kb  = Qb  + (size_t)NB * NTOK * HCH;
    unsigned short* Vtb = Kb  + (size_t)NB * NTOK * HCH;
    unsigned short* Rt2 = Vtb + (size_t)NB * NTOK * HCH;

    wprep_kernel<<<dim3(64), 256, 0, stream>>>(wq, wk, wv, wo, Wt, WoT);
    proj_kernel<<<dim3(NB * 25, 2), 256, 0, stream>>>(rgb, hsi, Wt, Qb, Kb, Vtb);
    attn_kernel<<<dim3(NB * 100), 256, 0, stream>>>(Qb, Kb, Vtb, Rt2);
    outproj_kernel<<<dim3(NB, 8, 25), 256, 0, stream>>>(Rt2, WoT, out);
}